// Round 2
// baseline (183.515 us; speedup 1.0000x reference)
//
#include <hip/hip_runtime.h>

// ForwardKinematicsURDF: B*N nodes, N=64 chain per graph (parent[i] = i-1).
// One 64-lane wave per graph; lane n = node n. Affine prefix scan via DPP
// (row_shr 1/2/4/8 + row_bcast15/31) — the canonical CDNA wave64 scan idiom.
// DPP partner fetch is full-rate VALU: no ds_bpermute, no lgkmcnt chain.
//
// local L = Rz(rpy_z) @ Ry(rpy_y) @ Rx(rpy_x) @ Rz(x)
// G_i = G_{i-1} ∘ (L_i, xyz_i),  (R1,t1)∘(R2,t2) = (R1R2, R1 t2 + t1)
// rot_i = G_i.R ; gpos_i = G_i.t ; pos_i = gpos_i - xyz_0

#define DPP_ROW_SHR1    0x111
#define DPP_ROW_SHR2    0x112
#define DPP_ROW_SHR4    0x114
#define DPP_ROW_SHR8    0x118
#define DPP_ROW_BCAST15 0x142
#define DPP_ROW_BCAST31 0x143

template<int CTRL, int RM>
__device__ __forceinline__ float dppf(float oldv, float src) {
    union { float f; int i; } o, s, r;
    o.f = oldv; s.f = src;
    // invalid/masked lanes keep `oldv` (we preload the identity transform)
    r.i = __builtin_amdgcn_update_dpp(o.i, s.i, CTRL, RM, 0xF, false);
    return r.f;
}

// one Hillis-Steele step: fetch partner (earlier prefix) via DPP, compose
// a <- p ∘ a. Lanes without a partner get p = identity -> no-op.
template<int CTRL, int RM>
__device__ __forceinline__ void scan_step(
    float& R00, float& R01, float& R02,
    float& R10, float& R11, float& R12,
    float& R20, float& R21, float& R22,
    float& t0,  float& t1,  float& t2)
{
    const float p00 = dppf<CTRL, RM>(1.0f, R00);
    const float p01 = dppf<CTRL, RM>(0.0f, R01);
    const float p02 = dppf<CTRL, RM>(0.0f, R02);
    const float p10 = dppf<CTRL, RM>(0.0f, R10);
    const float p11 = dppf<CTRL, RM>(1.0f, R11);
    const float p12 = dppf<CTRL, RM>(0.0f, R12);
    const float p20 = dppf<CTRL, RM>(0.0f, R20);
    const float p21 = dppf<CTRL, RM>(0.0f, R21);
    const float p22 = dppf<CTRL, RM>(1.0f, R22);
    const float q0  = dppf<CTRL, RM>(0.0f, t0);
    const float q1  = dppf<CTRL, RM>(0.0f, t1);
    const float q2  = dppf<CTRL, RM>(0.0f, t2);

    const float n00 = p00 * R00 + p01 * R10 + p02 * R20;
    const float n01 = p00 * R01 + p01 * R11 + p02 * R21;
    const float n02 = p00 * R02 + p01 * R12 + p02 * R22;
    const float n10 = p10 * R00 + p11 * R10 + p12 * R20;
    const float n11 = p10 * R01 + p11 * R11 + p12 * R21;
    const float n12 = p10 * R02 + p11 * R12 + p12 * R22;
    const float n20 = p20 * R00 + p21 * R10 + p22 * R20;
    const float n21 = p20 * R01 + p21 * R11 + p22 * R21;
    const float n22 = p20 * R02 + p21 * R12 + p22 * R22;
    const float u0  = p00 * t0 + p01 * t1 + p02 * t2 + q0;
    const float u1  = p10 * t0 + p11 * t1 + p12 * t2 + q1;
    const float u2  = p20 * t0 + p21 * t1 + p22 * t2 + q2;
    R00 = n00; R01 = n01; R02 = n02;
    R10 = n10; R11 = n11; R12 = n12;
    R20 = n20; R21 = n21; R22 = n22;
    t0 = u0;  t1 = u1;  t2 = u2;
}

__global__ __launch_bounds__(256) void fk_scan_kernel(
    const float* __restrict__ x,
    const float* __restrict__ offset,
    float* __restrict__ out,
    int BN)
{
    const int gid = blockIdx.x * blockDim.x + threadIdx.x; // b*64 + n
    if (gid >= BN) return;

    // ---- load (coalesced) ----
    const float ang = x[gid];
    const float2* off2 = (const float2*)offset;
    const float2 o0 = off2[gid * 3 + 0]; // tx, ty
    const float2 o1 = off2[gid * 3 + 1]; // tz, rx
    const float2 o2 = off2[gid * 3 + 2]; // ry, rz

    const float tx = o0.x, ty = o0.y, tz = o1.x;
    const float rx = o1.y, ry = o2.x, rz = o2.y;

    float sx, cx, sy, cy, sz, cz, st, ct;
    __sincosf(rx, &sx, &cx);
    __sincosf(ry, &sy, &cy);
    __sincosf(rz, &sz, &cz);
    __sincosf(ang, &st, &ct);

    // ---- Rrpy = Rz(rz) @ Ry(ry) @ Rx(rx) ----
    const float m00 = cz * cy, m01 = cz * sy * sx - sz * cx, m02 = cz * sy * cx + sz * sx;
    const float m10 = sz * cy, m11 = sz * sy * sx + cz * cx, m12 = sz * sy * cx - cz * sx;
    const float m20 = -sy,     m21 = cy * sx,                m22 = cy * cx;

    // ---- local = Rrpy @ Rz(ang)  (only first two columns mix) ----
    float R00 = m00 * ct + m01 * st, R01 = m01 * ct - m00 * st, R02 = m02;
    float R10 = m10 * ct + m11 * st, R11 = m11 * ct - m10 * st, R12 = m12;
    float R20 = m20 * ct + m21 * st, R21 = m21 * ct - m20 * st, R22 = m22;
    float t0 = tx, t1 = ty, t2 = tz;

    // xyz of node 0 (broadcast BEFORE scan mutates t)
    const float x00 = __shfl(tx, 0, 64);
    const float x01 = __shfl(ty, 0, 64);
    const float x02 = __shfl(tz, 0, 64);

    // ---- inclusive affine scan over 64 lanes, 6 DPP compose steps ----
    scan_step<DPP_ROW_SHR1,    0xF>(R00,R01,R02,R10,R11,R12,R20,R21,R22,t0,t1,t2);
    scan_step<DPP_ROW_SHR2,    0xF>(R00,R01,R02,R10,R11,R12,R20,R21,R22,t0,t1,t2);
    scan_step<DPP_ROW_SHR4,    0xF>(R00,R01,R02,R10,R11,R12,R20,R21,R22,t0,t1,t2);
    scan_step<DPP_ROW_SHR8,    0xF>(R00,R01,R02,R10,R11,R12,R20,R21,R22,t0,t1,t2);
    scan_step<DPP_ROW_BCAST15, 0xA>(R00,R01,R02,R10,R11,R12,R20,R21,R22,t0,t1,t2);
    scan_step<DPP_ROW_BCAST31, 0xC>(R00,R01,R02,R10,R11,R12,R20,R21,R22,t0,t1,t2);

    // ---- epilogue ----
    const float g0 = t0, g1 = t1, g2 = t2;                    // gpos
    const float p0 = g0 - x00, p1 = g1 - x01, p2 = g2 - x02;  // pos

    // out = [pos (BN*3) | rot (BN*9) | gpos (BN*3)]
    float* __restrict__ posp = out;
    float* __restrict__ rotp = out + (size_t)BN * 3;
    float* __restrict__ gpp  = out + (size_t)BN * 12;

    posp[gid * 3 + 0] = p0;
    posp[gid * 3 + 1] = p1;
    posp[gid * 3 + 2] = p2;

    rotp[gid * 9 + 0] = R00; rotp[gid * 9 + 1] = R01; rotp[gid * 9 + 2] = R02;
    rotp[gid * 9 + 3] = R10; rotp[gid * 9 + 4] = R11; rotp[gid * 9 + 5] = R12;
    rotp[gid * 9 + 6] = R20; rotp[gid * 9 + 7] = R21; rotp[gid * 9 + 8] = R22;

    gpp[gid * 3 + 0] = g0;
    gpp[gid * 3 + 1] = g1;
    gpp[gid * 3 + 2] = g2;
}

extern "C" void kernel_launch(void* const* d_in, const int* in_sizes, int n_in,
                              void* d_out, int out_size, void* d_ws, size_t ws_size,
                              hipStream_t stream) {
    const float* x      = (const float*)d_in[0];
    // d_in[1] = parent (unused: chain structure parent[i] = i-1 per setup)
    const float* offset = (const float*)d_in[2];
    float* out = (float*)d_out;

    const int BN = in_sizes[0];          // B * N, N = 64
    const int block = 256;               // 4 waves = 4 graphs per block
    const int grid = (BN + block - 1) / block;
    fk_scan_kernel<<<grid, block, 0, stream>>>(x, offset, out, BN);
}

// Round 3
// 177.080 us; speedup vs baseline: 1.0363x; 1.0363x over previous
//
#include <hip/hip_runtime.h>

// ForwardKinematicsURDF: B*N nodes, N=64 chain per graph (parent[i] = i-1).
// One 64-lane wave per graph; lane n = node n. Affine prefix scan via DPP.
// Outputs staged through LDS -> fully-coalesced float4 stores (the scalar
// strided stores cost ~6.6x the minimal 64B-transaction count).
//
// local L = Rz(rpy_z) @ Ry(rpy_y) @ Rx(rpy_x) @ Rz(x)
// G_i = G_{i-1} ∘ (L_i, xyz_i),  (R1,t1)∘(R2,t2) = (R1R2, R1 t2 + t1)
// rot_i = G_i.R ; gpos_i = G_i.t ; pos_i = gpos_i - xyz_0

#define DPP_ROW_SHR1    0x111
#define DPP_ROW_SHR2    0x112
#define DPP_ROW_SHR4    0x114
#define DPP_ROW_SHR8    0x118
#define DPP_ROW_BCAST15 0x142
#define DPP_ROW_BCAST31 0x143

template<int CTRL, int RM>
__device__ __forceinline__ float dppf(float oldv, float src) {
    union { float f; int i; } o, s, r;
    o.f = oldv; s.f = src;
    // invalid/masked lanes keep `oldv` (we preload the identity transform)
    r.i = __builtin_amdgcn_update_dpp(o.i, s.i, CTRL, RM, 0xF, false);
    return r.f;
}

template<int CTRL, int RM>
__device__ __forceinline__ void scan_step(
    float& R00, float& R01, float& R02,
    float& R10, float& R11, float& R12,
    float& R20, float& R21, float& R22,
    float& t0,  float& t1,  float& t2)
{
    const float p00 = dppf<CTRL, RM>(1.0f, R00);
    const float p01 = dppf<CTRL, RM>(0.0f, R01);
    const float p02 = dppf<CTRL, RM>(0.0f, R02);
    const float p10 = dppf<CTRL, RM>(0.0f, R10);
    const float p11 = dppf<CTRL, RM>(1.0f, R11);
    const float p12 = dppf<CTRL, RM>(0.0f, R12);
    const float p20 = dppf<CTRL, RM>(0.0f, R20);
    const float p21 = dppf<CTRL, RM>(0.0f, R21);
    const float p22 = dppf<CTRL, RM>(1.0f, R22);
    const float q0  = dppf<CTRL, RM>(0.0f, t0);
    const float q1  = dppf<CTRL, RM>(0.0f, t1);
    const float q2  = dppf<CTRL, RM>(0.0f, t2);

    const float n00 = p00 * R00 + p01 * R10 + p02 * R20;
    const float n01 = p00 * R01 + p01 * R11 + p02 * R21;
    const float n02 = p00 * R02 + p01 * R12 + p02 * R22;
    const float n10 = p10 * R00 + p11 * R10 + p12 * R20;
    const float n11 = p10 * R01 + p11 * R11 + p12 * R21;
    const float n12 = p10 * R02 + p11 * R12 + p12 * R22;
    const float n20 = p20 * R00 + p21 * R10 + p22 * R20;
    const float n21 = p20 * R01 + p21 * R11 + p22 * R21;
    const float n22 = p20 * R02 + p21 * R12 + p22 * R22;
    const float u0  = p00 * t0 + p01 * t1 + p02 * t2 + q0;
    const float u1  = p10 * t0 + p11 * t1 + p12 * t2 + q1;
    const float u2  = p20 * t0 + p21 * t1 + p22 * t2 + q2;
    R00 = n00; R01 = n01; R02 = n02;
    R10 = n10; R11 = n11; R12 = n12;
    R20 = n20; R21 = n21; R22 = n22;
    t0 = u0;  t1 = u1;  t2 = u2;
}

__global__ __launch_bounds__(256) void fk_scan_kernel(
    const float* __restrict__ x,
    const float* __restrict__ offset,
    float* __restrict__ out,
    int BN)
{
    // LDS staging: [pos 256*3 | rot 256*9 | gpos 256*3] floats = 15360 B
    __shared__ float lds[256 * 15];

    const int tid = threadIdx.x;
    const int gid = blockIdx.x * 256 + tid; // BN % 256 == 0 (B=32768, N=64)

    // ---- load (coalesced) ----
    const float ang = x[gid];
    const float2* off2 = (const float2*)offset;
    const float2 o0 = off2[gid * 3 + 0]; // tx, ty
    const float2 o1 = off2[gid * 3 + 1]; // tz, rx
    const float2 o2 = off2[gid * 3 + 2]; // ry, rz

    const float tx = o0.x, ty = o0.y, tz = o1.x;
    const float rx = o1.y, ry = o2.x, rz = o2.y;

    float sx, cx, sy, cy, sz, cz, st, ct;
    __sincosf(rx, &sx, &cx);
    __sincosf(ry, &sy, &cy);
    __sincosf(rz, &sz, &cz);
    __sincosf(ang, &st, &ct);

    // ---- Rrpy = Rz(rz) @ Ry(ry) @ Rx(rx) ----
    const float m00 = cz * cy, m01 = cz * sy * sx - sz * cx, m02 = cz * sy * cx + sz * sx;
    const float m10 = sz * cy, m11 = sz * sy * sx + cz * cx, m12 = sz * sy * cx - cz * sx;
    const float m20 = -sy,     m21 = cy * sx,                m22 = cy * cx;

    // ---- local = Rrpy @ Rz(ang) ----
    float R00 = m00 * ct + m01 * st, R01 = m01 * ct - m00 * st, R02 = m02;
    float R10 = m10 * ct + m11 * st, R11 = m11 * ct - m10 * st, R12 = m12;
    float R20 = m20 * ct + m21 * st, R21 = m21 * ct - m20 * st, R22 = m22;
    float t0 = tx, t1 = ty, t2 = tz;

    // xyz of node 0 of this wave's graph (broadcast BEFORE scan mutates t)
    union { float f; int i; } ux, uy, uz;
    ux.f = tx; uy.f = ty; uz.f = tz;
    ux.i = __builtin_amdgcn_readlane(ux.i, 0);
    uy.i = __builtin_amdgcn_readlane(uy.i, 0);
    uz.i = __builtin_amdgcn_readlane(uz.i, 0);
    const float x00 = ux.f, x01 = uy.f, x02 = uz.f;

    // ---- inclusive affine scan over 64 lanes, 6 DPP compose steps ----
    scan_step<DPP_ROW_SHR1,    0xF>(R00,R01,R02,R10,R11,R12,R20,R21,R22,t0,t1,t2);
    scan_step<DPP_ROW_SHR2,    0xF>(R00,R01,R02,R10,R11,R12,R20,R21,R22,t0,t1,t2);
    scan_step<DPP_ROW_SHR4,    0xF>(R00,R01,R02,R10,R11,R12,R20,R21,R22,t0,t1,t2);
    scan_step<DPP_ROW_SHR8,    0xF>(R00,R01,R02,R10,R11,R12,R20,R21,R22,t0,t1,t2);
    scan_step<DPP_ROW_BCAST15, 0xA>(R00,R01,R02,R10,R11,R12,R20,R21,R22,t0,t1,t2);
    scan_step<DPP_ROW_BCAST31, 0xC>(R00,R01,R02,R10,R11,R12,R20,R21,R22,t0,t1,t2);

    // ---- epilogue: stage to LDS (strides 3 & 9 dwords: 2 lanes/bank, free) ----
    const float g0 = t0, g1 = t1, g2 = t2;                    // gpos
    const float p0 = g0 - x00, p1 = g1 - x01, p2 = g2 - x02;  // pos

    lds[tid * 3 + 0] = p0;
    lds[tid * 3 + 1] = p1;
    lds[tid * 3 + 2] = p2;

    float* lrot = lds + 768;
    lrot[tid * 9 + 0] = R00; lrot[tid * 9 + 1] = R01; lrot[tid * 9 + 2] = R02;
    lrot[tid * 9 + 3] = R10; lrot[tid * 9 + 4] = R11; lrot[tid * 9 + 5] = R12;
    lrot[tid * 9 + 6] = R20; lrot[tid * 9 + 7] = R21; lrot[tid * 9 + 8] = R22;

    float* lgp = lds + 3072;
    lgp[tid * 3 + 0] = g0;
    lgp[tid * 3 + 1] = g1;
    lgp[tid * 3 + 2] = g2;

    __syncthreads();

    // ---- coalesced float4 copy-out ----
    // out = [pos (BN*3) | rot (BN*9) | gpos (BN*3)], block covers 256 nodes
    const size_t blockbase = (size_t)blockIdx.x * 256;
    const float4* l4 = (const float4*)lds;
    float4* pos4 = (float4*)(out + blockbase * 3);
    float4* rot4 = (float4*)(out + (size_t)BN * 3 + blockbase * 9);
    float4* gp4  = (float4*)(out + (size_t)BN * 12 + blockbase * 3);

    if (tid < 192) pos4[tid] = l4[tid];                 // 192 float4 = 3072 B
    rot4[tid]       = l4[192 + tid];                    // 576 float4 = 9216 B
    rot4[tid + 256] = l4[192 + 256 + tid];
    if (tid < 64) rot4[tid + 512] = l4[192 + 512 + tid];
    if (tid < 192) gp4[tid] = l4[768 + tid];            // 192 float4 = 3072 B
}

extern "C" void kernel_launch(void* const* d_in, const int* in_sizes, int n_in,
                              void* d_out, int out_size, void* d_ws, size_t ws_size,
                              hipStream_t stream) {
    const float* x      = (const float*)d_in[0];
    // d_in[1] = parent (unused: chain structure parent[i] = i-1 per setup)
    const float* offset = (const float*)d_in[2];
    float* out = (float*)d_out;

    const int BN = in_sizes[0];          // B * N, N = 64, divisible by 256
    const int block = 256;               // 4 waves = 4 graphs per block
    const int grid = BN / block;
    fk_scan_kernel<<<grid, block, 0, stream>>>(x, offset, out, BN);
}

// Round 4
// 176.869 us; speedup vs baseline: 1.0376x; 1.0012x over previous
//
#include <hip/hip_runtime.h>

// ForwardKinematicsURDF: B*N nodes, N=64 chain per graph (parent[i] = i-1).
// One 64-lane wave per graph; lane n = node n. Affine prefix scan via DPP.
// Inputs AND outputs staged through LDS for fully-coalesced global access
// (validated model: ~1 transaction/cycle/CU; strided lane access inflates
// transaction count 3-6x).
//
// local L = Rz(rpy_z) @ Ry(rpy_y) @ Rx(rpy_x) @ Rz(x)
// G_i = G_{i-1} ∘ (L_i, xyz_i),  (R1,t1)∘(R2,t2) = (R1R2, R1 t2 + t1)
// rot_i = G_i.R ; gpos_i = G_i.t ; pos_i = gpos_i - xyz_0

#define DPP_ROW_SHR1    0x111
#define DPP_ROW_SHR2    0x112
#define DPP_ROW_SHR4    0x114
#define DPP_ROW_SHR8    0x118
#define DPP_ROW_BCAST15 0x142
#define DPP_ROW_BCAST31 0x143

template<int CTRL, int RM>
__device__ __forceinline__ float dppf(float oldv, float src) {
    union { float f; int i; } o, s, r;
    o.f = oldv; s.f = src;
    // invalid/masked lanes keep `oldv` (we preload the identity transform)
    r.i = __builtin_amdgcn_update_dpp(o.i, s.i, CTRL, RM, 0xF, false);
    return r.f;
}

template<int CTRL, int RM>
__device__ __forceinline__ void scan_step(
    float& R00, float& R01, float& R02,
    float& R10, float& R11, float& R12,
    float& R20, float& R21, float& R22,
    float& t0,  float& t1,  float& t2)
{
    const float p00 = dppf<CTRL, RM>(1.0f, R00);
    const float p01 = dppf<CTRL, RM>(0.0f, R01);
    const float p02 = dppf<CTRL, RM>(0.0f, R02);
    const float p10 = dppf<CTRL, RM>(0.0f, R10);
    const float p11 = dppf<CTRL, RM>(1.0f, R11);
    const float p12 = dppf<CTRL, RM>(0.0f, R12);
    const float p20 = dppf<CTRL, RM>(0.0f, R20);
    const float p21 = dppf<CTRL, RM>(0.0f, R21);
    const float p22 = dppf<CTRL, RM>(1.0f, R22);
    const float q0  = dppf<CTRL, RM>(0.0f, t0);
    const float q1  = dppf<CTRL, RM>(0.0f, t1);
    const float q2  = dppf<CTRL, RM>(0.0f, t2);

    const float n00 = p00 * R00 + p01 * R10 + p02 * R20;
    const float n01 = p00 * R01 + p01 * R11 + p02 * R21;
    const float n02 = p00 * R02 + p01 * R12 + p02 * R22;
    const float n10 = p10 * R00 + p11 * R10 + p12 * R20;
    const float n11 = p10 * R01 + p11 * R11 + p12 * R21;
    const float n12 = p10 * R02 + p11 * R12 + p12 * R22;
    const float n20 = p20 * R00 + p21 * R10 + p22 * R20;
    const float n21 = p20 * R01 + p21 * R11 + p22 * R21;
    const float n22 = p20 * R02 + p21 * R12 + p22 * R22;
    const float u0  = p00 * t0 + p01 * t1 + p02 * t2 + q0;
    const float u1  = p10 * t0 + p11 * t1 + p12 * t2 + q1;
    const float u2  = p20 * t0 + p21 * t1 + p22 * t2 + q2;
    R00 = n00; R01 = n01; R02 = n02;
    R10 = n10; R11 = n11; R12 = n12;
    R20 = n20; R21 = n21; R22 = n22;
    t0 = u0;  t1 = u1;  t2 = u2;
}

__global__ __launch_bounds__(256) void fk_scan_kernel(
    const float* __restrict__ x,
    const float* __restrict__ offset,
    float* __restrict__ out,
    int BN)
{
    // 15360 B, reused: phase 1 = input staging (1792 floats, stride-7 pad),
    // phase 2 = output staging [pos 768 | rot 2304 | gpos 768] floats.
    __shared__ float lds[256 * 15];

    const int tid = threadIdx.x;
    const int gid = blockIdx.x * 256 + tid; // BN % 256 == 0 (B=32768, N=64)

    // ---- phase 1: cooperative coalesced input staging ----
    // block's offset slice: 256 nodes * 3 float2 = 768 float2 (6144 B)
    {
        const float2* src = ((const float2*)offset) + (size_t)blockIdx.x * 768;
        #pragma unroll
        for (int k = 0; k < 3; ++k) {
            const int i = tid + k * 256;        // float2 index within block
            const float2 v = src[i];            // lane-consecutive: minimal lines
            const int node = i / 3;
            const int comp = i - node * 3;
            lds[node * 7 + comp * 2]     = v.x; // stride-7 pad: conflict-free reads
            lds[node * 7 + comp * 2 + 1] = v.y;
        }
    }
    const float ang = x[gid];                   // 4 lines/wave: already minimal
    __syncthreads();

    const float tx = lds[tid * 7 + 0], ty = lds[tid * 7 + 1], tz = lds[tid * 7 + 2];
    const float rx = lds[tid * 7 + 3], ry = lds[tid * 7 + 4], rz = lds[tid * 7 + 5];
    __syncthreads();                            // LDS reused for outputs below

    float sx, cx, sy, cy, sz, cz, st, ct;
    __sincosf(rx, &sx, &cx);
    __sincosf(ry, &sy, &cy);
    __sincosf(rz, &sz, &cz);
    __sincosf(ang, &st, &ct);

    // ---- Rrpy = Rz(rz) @ Ry(ry) @ Rx(rx) ----
    const float m00 = cz * cy, m01 = cz * sy * sx - sz * cx, m02 = cz * sy * cx + sz * sx;
    const float m10 = sz * cy, m11 = sz * sy * sx + cz * cx, m12 = sz * sy * cx - cz * sx;
    const float m20 = -sy,     m21 = cy * sx,                m22 = cy * cx;

    // ---- local = Rrpy @ Rz(ang) ----
    float R00 = m00 * ct + m01 * st, R01 = m01 * ct - m00 * st, R02 = m02;
    float R10 = m10 * ct + m11 * st, R11 = m11 * ct - m10 * st, R12 = m12;
    float R20 = m20 * ct + m21 * st, R21 = m21 * ct - m20 * st, R22 = m22;
    float t0 = tx, t1 = ty, t2 = tz;

    // xyz of node 0 of this wave's graph (broadcast BEFORE scan mutates t)
    union { float f; int i; } ux, uy, uz;
    ux.f = tx; uy.f = ty; uz.f = tz;
    ux.i = __builtin_amdgcn_readlane(ux.i, 0);
    uy.i = __builtin_amdgcn_readlane(uy.i, 0);
    uz.i = __builtin_amdgcn_readlane(uz.i, 0);
    const float x00 = ux.f, x01 = uy.f, x02 = uz.f;

    // ---- inclusive affine scan over 64 lanes, 6 DPP compose steps ----
    scan_step<DPP_ROW_SHR1,    0xF>(R00,R01,R02,R10,R11,R12,R20,R21,R22,t0,t1,t2);
    scan_step<DPP_ROW_SHR2,    0xF>(R00,R01,R02,R10,R11,R12,R20,R21,R22,t0,t1,t2);
    scan_step<DPP_ROW_SHR4,    0xF>(R00,R01,R02,R10,R11,R12,R20,R21,R22,t0,t1,t2);
    scan_step<DPP_ROW_SHR8,    0xF>(R00,R01,R02,R10,R11,R12,R20,R21,R22,t0,t1,t2);
    scan_step<DPP_ROW_BCAST15, 0xA>(R00,R01,R02,R10,R11,R12,R20,R21,R22,t0,t1,t2);
    scan_step<DPP_ROW_BCAST31, 0xC>(R00,R01,R02,R10,R11,R12,R20,R21,R22,t0,t1,t2);

    // ---- phase 2: stage outputs to LDS (strides 3 & 9 dwords: free) ----
    const float g0 = t0, g1 = t1, g2 = t2;                    // gpos
    const float p0 = g0 - x00, p1 = g1 - x01, p2 = g2 - x02;  // pos

    lds[tid * 3 + 0] = p0;
    lds[tid * 3 + 1] = p1;
    lds[tid * 3 + 2] = p2;

    float* lrot = lds + 768;
    lrot[tid * 9 + 0] = R00; lrot[tid * 9 + 1] = R01; lrot[tid * 9 + 2] = R02;
    lrot[tid * 9 + 3] = R10; lrot[tid * 9 + 4] = R11; lrot[tid * 9 + 5] = R12;
    lrot[tid * 9 + 6] = R20; lrot[tid * 9 + 7] = R21; lrot[tid * 9 + 8] = R22;

    float* lgp = lds + 3072;
    lgp[tid * 3 + 0] = g0;
    lgp[tid * 3 + 1] = g1;
    lgp[tid * 3 + 2] = g2;

    __syncthreads();

    // ---- coalesced float4 copy-out ----
    // out = [pos (BN*3) | rot (BN*9) | gpos (BN*3)], block covers 256 nodes
    const size_t blockbase = (size_t)blockIdx.x * 256;
    const float4* l4 = (const float4*)lds;
    float4* pos4 = (float4*)(out + blockbase * 3);
    float4* rot4 = (float4*)(out + (size_t)BN * 3 + blockbase * 9);
    float4* gp4  = (float4*)(out + (size_t)BN * 12 + blockbase * 3);

    if (tid < 192) pos4[tid] = l4[tid];                 // 192 float4 = 3072 B
    rot4[tid]       = l4[192 + tid];                    // 576 float4 = 9216 B
    rot4[tid + 256] = l4[192 + 256 + tid];
    if (tid < 64) rot4[tid + 512] = l4[192 + 512 + tid];
    if (tid < 192) gp4[tid] = l4[768 + tid];            // 192 float4 = 3072 B
}

extern "C" void kernel_launch(void* const* d_in, const int* in_sizes, int n_in,
                              void* d_out, int out_size, void* d_ws, size_t ws_size,
                              hipStream_t stream) {
    const float* x      = (const float*)d_in[0];
    // d_in[1] = parent (unused: chain structure parent[i] = i-1 per setup)
    const float* offset = (const float*)d_in[2];
    float* out = (float*)d_out;

    const int BN = in_sizes[0];          // B * N, N = 64, divisible by 256
    const int block = 256;               // 4 waves = 4 graphs per block
    const int grid = BN / block;
    fk_scan_kernel<<<grid, block, 0, stream>>>(x, offset, out, BN);
}